// Round 4
// baseline (104.944 us; speedup 1.0000x reference)
//
#include <hip/hip_runtime.h>
#include <hip/hip_bf16.h>

// u[b,o,y,x] = sum_d dist(p,d) * t[b,d,o],  t = v@W^T + bias
// GEMM: out[col*9216 + p] = sum_d D[p,d] * T2[col][d],  col = b*32+o
// D generated in registers. 32x32x16 MFMA, 2x4 reg tile per wave,
// block 128 rows x 256 cols, K split 8 ways (1 chunk per XCD).

typedef __bf16 bf16x8 __attribute__((ext_vector_type(8)));
typedef float  f32x4  __attribute__((ext_vector_type(4)));
typedef float  f32x16 __attribute__((ext_vector_type(16)));

#define NPTS   9216      // 96*96
#define CIN    32
#define COUT   32
#define NCOLS  256       // 8 batches * 32 cout
#define SCALE  (1.0f / 95.0f)
#define OUTN   (NCOLS * NPTS)

// ---------------- Kernel 1: projection  T2[col][d] = bf16(v . W^T + b) ----
__global__ __launch_bounds__(256) void proj_kernel(
    const float* __restrict__ v, const float* __restrict__ W,
    const float* __restrict__ bias, __bf16* __restrict__ T2)
{
    __shared__ float Wl[COUT * CIN];
    __shared__ float bl[COUT];
    const int t = threadIdx.x;
    for (int i = t; i < COUT * CIN; i += 256) Wl[i] = W[i];
    if (t < COUT) bl[t] = bias[t];
    __syncthreads();

    const int b = blockIdx.y;
    const int d = blockIdx.x * 256 + t;
    const float* vb = v + (size_t)b * CIN * NPTS + d;

    float acc[COUT];
#pragma unroll
    for (int o = 0; o < COUT; ++o) acc[o] = bl[o];
#pragma unroll 4
    for (int c = 0; c < CIN; ++c) {
        const float vv = vb[(size_t)c * NPTS];
#pragma unroll
        for (int o = 0; o < COUT; ++o) acc[o] += vv * Wl[o * CIN + c];
    }
#pragma unroll
    for (int o = 0; o < COUT; ++o)
        T2[(size_t)(b * COUT + o) * NPTS + d] = (__bf16)acc[o];
}

// ---------------- A-fragment generator -----------------------------------
__device__ __forceinline__ bf16x8 agen(float dx, float dy2) {
    bf16x8 a;
#pragma unroll
    for (int j = 0; j < 8; ++j) {
        const float s2 = __builtin_fmaf(dx, dx, dy2);
        a[j] = (__bf16)__builtin_amdgcn_sqrtf(s2);
        dx -= SCALE;
    }
    return a;
}

// ---------------- Kernel 2: implicit-D GEMM ------------------------------
// grid (72*nsplit): block = 128 rows x 256 cols x kchunk.
// 4 waves: 2 row-groups x 2 col-groups, each wave 64r x 128c (2x4 tiles
// of 32x32). LDS B-tile [256 col][64 k] bf16, 128B stride, XOR-swizzled
// byte^=(col&7)<<4; staged via global_load_lds with pre-swizzled source.
__global__ __launch_bounds__(256) void gemm_kernel(
    const __bf16* __restrict__ T2, float* __restrict__ dst,
    int nsplit, int kchunk, int usePartial)
{
    __shared__ __align__(1024) unsigned char lds[2][32768];

    const int tid  = threadIdx.x;
    const int wid  = tid >> 6;
    const int lane = tid & 63;
    const int l31  = lane & 31;
    const int hi   = lane >> 5;      // k-half within frag
    const int wr   = wid >> 1;       // row group 0..1
    const int wc   = wid & 1;        // col group 0..1

    const int bid = blockIdx.x;
    const int z   = bid % nsplit;    // k-chunk id == XCD id for nsplit=8
    const int x   = bid / nsplit;    // row-block id
    const int koff  = z * kchunk;
    const int iters = kchunk >> 6;   // BK = 64

    const int p0  = x * 128 + wr * 64;
    const int pr0 = p0 + l31;
    const int pr1 = pr0 + 32;
    const int yp0 = pr0 / 96, xp0 = pr0 - yp0 * 96;
    const int yp1 = pr1 / 96, xp1 = pr1 - yp1 * 96;
    const float yph0 = (float)yp0 * SCALE;
    const float yph1 = (float)yp1 * SCALE;
    const float xph0 = (float)(xp0 - hi * 8) * SCALE;
    const float xph1 = (float)(xp1 - hi * 8) * SCALE;

    // staging: thread t loads col c0(+32i), 16B chunk (t&7)^(c0&7); LDS
    // write is linear (base + lane*16) so the swizzle lands correctly.
    const int c0 = tid >> 3;
    const int ch = (tid & 7) ^ (c0 & 7);
    const __bf16* gsrc = T2 + (size_t)c0 * NPTS + ch * 8 + koff;
    const int ldst = tid * 16;

    auto stage = [&](int buf, int kt) {
#pragma unroll
        for (int i = 0; i < 8; ++i)
            __builtin_amdgcn_global_load_lds(
                (const __attribute__((address_space(1))) void*)
                    (gsrc + (size_t)kt * 64 + (size_t)i * 32 * NPTS),
                (__attribute__((address_space(3))) void*)
                    (&lds[buf][i * 4096 + ldst]),
                16, 0, 0);
    };

    f32x16 acc0[4], acc1[4];
#pragma unroll
    for (int n = 0; n < 4; ++n) {
        acc0[n] = (f32x16)(0.0f);
        acc1[n] = (f32x16)(0.0f);
    }

    stage(0, 0);
    __syncthreads();

    int   xbi = koff % 96;
    float xbf = (float)xbi * SCALE;
    float ydf = (float)(koff / 96) * SCALE;

    int cur = 0;
    for (int kt = 0; kt < iters; ++kt) {
        if (kt + 1 < iters) stage(cur ^ 1, kt + 1);
#pragma unroll
        for (int s = 0; s < 4; ++s) {       // 4 k-steps of 16
            const float dy0 = yph0 - ydf, dy20 = dy0 * dy0;
            const float dy1 = yph1 - ydf, dy21 = dy1 * dy1;
            const bf16x8 a0 = agen(xph0 - xbf, dy20);
            const bf16x8 a1 = agen(xph1 - xbf, dy21);
            const int kb = (s * 32 + hi * 16) ^ ((l31 & 7) << 4);
#pragma unroll
            for (int n = 0; n < 4; ++n) {
                const int col = wc * 128 + n * 32 + l31;
                const bf16x8 b = *(const bf16x8*)(&lds[cur][col * 128 + kb]);
                acc0[n] = __builtin_amdgcn_mfma_f32_32x32x16_bf16(
                    a0, b, acc0[n], 0, 0, 0);
                acc1[n] = __builtin_amdgcn_mfma_f32_32x32x16_bf16(
                    a1, b, acc1[n], 0, 0, 0);
            }
            xbi += 16; xbf += 16.0f * SCALE;
            if (xbi == 96) { xbi = 0; xbf = 0.0f; ydf += SCALE; }
        }
        __syncthreads();
        cur ^= 1;
    }

    // epilogue: 32x32 C/D: col=lane&31, row=(reg&3)+8*(reg>>2)+4*hi
    float* dp = usePartial ? (dst + (size_t)z * OUTN) : dst;
#pragma unroll
    for (int n = 0; n < 4; ++n) {
        const int col = wc * 128 + n * 32 + l31;
        float* b0 = dp + (size_t)col * NPTS + p0 + hi * 4;
        if (usePartial) {
#pragma unroll
            for (int q = 0; q < 4; ++q) {
                f32x4 v0 = { acc0[n][4*q], acc0[n][4*q+1],
                             acc0[n][4*q+2], acc0[n][4*q+3] };
                f32x4 v1 = { acc1[n][4*q], acc1[n][4*q+1],
                             acc1[n][4*q+2], acc1[n][4*q+3] };
                *(f32x4*)(b0 + q * 8)      = v0;
                *(f32x4*)(b0 + 32 + q * 8) = v1;
            }
        } else {
#pragma unroll
            for (int q = 0; q < 4; ++q)
#pragma unroll
                for (int r = 0; r < 4; ++r) {
                    atomicAdd(b0 + q * 8 + r,      acc0[n][4*q+r]);
                    atomicAdd(b0 + 32 + q * 8 + r, acc1[n][4*q+r]);
                }
        }
    }
}

// ---------------- Kernel 3: reduce nsplit partials ------------------------
__global__ __launch_bounds__(256) void reduce_kernel(
    const float* __restrict__ part, float* __restrict__ out, int nsplit)
{
    const size_t i = ((size_t)blockIdx.x * 256 + threadIdx.x) * 4;
    f32x4 a = *(const f32x4*)(part + i);
    for (int s = 1; s < nsplit; ++s)
        a += *(const f32x4*)(part + (size_t)s * OUTN + i);
    *(f32x4*)(out + i) = a;
}

extern "C" void kernel_launch(void* const* d_in, const int* in_sizes, int n_in,
                              void* d_out, int out_size, void* d_ws, size_t ws_size,
                              hipStream_t stream) {
    const float* v    = (const float*)d_in[0];  // (8,32,96,96)
    const float* W    = (const float*)d_in[1];  // (32,32)
    const float* bias = (const float*)d_in[2];  // (32,)
    float* out = (float*)d_out;                 // (8,32,96,96) f32
    __bf16* T2 = (__bf16*)d_ws;                 // 256 x 9216 bf16 = 4.72 MB

    const size_t t2b = (size_t)NCOLS * NPTS * 2;
    int nsplit = 0;
    if      (ws_size >= t2b + 8ull * OUTN * 4) nsplit = 8;
    else if (ws_size >= t2b + 4ull * OUTN * 4) nsplit = 4;
    float* partial = (float*)((char*)d_ws + t2b);

    proj_kernel<<<dim3(36, 8), 256, 0, stream>>>(v, W, bias, T2);
    if (nsplit) {
        gemm_kernel<<<72 * nsplit, 256, 0, stream>>>(
            T2, partial, nsplit, NPTS / nsplit, 1);
        reduce_kernel<<<OUTN / 1024, 256, 0, stream>>>(partial, out, nsplit);
    } else {
        hipMemsetAsync(d_out, 0, (size_t)out_size * sizeof(float), stream);
        gemm_kernel<<<72 * 8, 256, 0, stream>>>(T2, out, 8, NPTS / 8, 0);
    }
}